// Round 13
// baseline (211.400 us; speedup 1.0000x reference)
//
#include <hip/hip_runtime.h>
#include <hip/hip_bf16.h>
#include <stdint.h>

// Problem: 3x Bahdanau attention (p/c/h heads) -> averaged softmax weights -> weighted sum of sentence.
// S=8192, H2=1024, A=2048, E=768. All inputs fp32; output fp32 [1024].
// R13 (205.9us): 64x64 wave tile, zero-LDS frag-major gemm -> gemm fell out of top-5 (<40.6us;
//     predicted ~35). Loads/MFMA model confirmed 3x: 1.1->54.6, 0.75->47.8, 0.5->~36.
//     Top-5 now = harness 256MiB fillBufferAligned re-poison (~41us each, fixed).
//     Ledger: rest ~170 => R13's phase-1 flip (coalesced-READ) regressed prep ~5us vs R12's
//     dst-linear (coalesced-WRITE) -- writes are the side that must coalesce (matches R11->R12).
// R14: gemm untouched. (a) prep phase-1 reverted to R12 dst-linear mapping (1KB/wave writes,
//     64B-granular reads), guard updated for 128-row m-tiles; (b) k_out stats 2 passes -> 1
//     online (max,sum) pass with online-merge shuffle reduction.
// Next gemm ratio step (64x128 wave tile) ruled out: ~240 VGPR -> 1.5 waves/SIMD TLP collapse.

namespace {

constexpr int S = 8192;
constexpr int H = 1024;   // H2
constexpr int A = 2048;
constexpr int E = 768;

typedef __bf16 bf16x8 __attribute__((ext_vector_type(8)));
typedef float f32x4 __attribute__((ext_vector_type(4)));

__device__ __forceinline__ bf16x8 cvt8(float4 lo, float4 hi) {
  bf16x8 r;
  r[0] = (__bf16)lo.x; r[1] = (__bf16)lo.y; r[2] = (__bf16)lo.z; r[3] = (__bf16)lo.w;
  r[4] = (__bf16)hi.x; r[5] = (__bf16)hi.y; r[6] = (__bf16)hi.z; r[7] = (__bf16)hi.w;
  return r;
}

// ---------- merged prep ----------
// packA seg layout (1KB = 512 bf16): seg = g*64 + kt*2 + f; elem (quad*16+l16)*8+e =
//   sentence[g*32 + f*16 + l16][kt*32 + quad*8 + e]   (g: 32-row group, kt: k-tile of 32)
// packB seg layout: seg = (head*128 + cg)*32 + kt; elem (quad*16+l16)*8+e =
//   W_sent[kt*32+quad*8+e][cg*16+l16]                 (cg: 16-col group of A-dim)
// [0,4096)      phase 1: pack sentence -> packA, DST-LINEAR (R12 mapping: consecutive t ->
//               consecutive 16B writes, 1KB/wave; reads 64B-granular). Rows < round_up(len,128).
// [4096,5632)   phase 2: W_sent [H][A] -> packB frag-major via LDS transpose tile
// [5632,5728)   phase 3: ctxb_q[q][head][a] partial ctx @ W_ctx (+biases in q0)
// [5728,5736)   phase 4: zero e_arr + out
__global__ __launch_bounds__(256)
void k_prep(const float* __restrict__ sentence, __bf16* __restrict__ packA,
            const float* __restrict__ Wp, const float* __restrict__ Wc_s,
            const float* __restrict__ Wh, __bf16* __restrict__ packB,
            const float* __restrict__ ctx_p, const float* __restrict__ ctx_c,
            const float* __restrict__ ctx_h,
            const float* __restrict__ Wcx_p, const float* __restrict__ Wcx_c,
            const float* __restrict__ Wcx_h,
            const float* __restrict__ bs_p, const float* __restrict__ bs_c,
            const float* __restrict__ bs_h,
            const float* __restrict__ bc_p, const float* __restrict__ bc_c,
            const float* __restrict__ bc_h,
            float* __restrict__ ctxb_q, float* __restrict__ e_arr,
            const int* __restrict__ length, float* __restrict__ out, int n_out) {
  __shared__ float tile[64][65];
  int b = blockIdx.x;
  int t = threadIdx.x;

  if (b < 4096) {
    // ---- phase 1: dst-linear A-pack (R12 mapping). Block b owns segs [b*4, b*4+4).
    int len = min(max(length[0], 0), S);
    int lenp = (len + 127) & ~127;        // GEMM m-tiles are 128 rows
    if ((b >> 4) * 32 >= lenp) return;    // b>>4 == row-group g of all 4 segs
    int C = b * 256 + t;                  // global 16B chunk id
    int seg = C >> 6;
    int g = seg >> 6, kt = (seg >> 1) & 31, f = seg & 1;
    int slot = C & 63, quad = slot >> 4, l16 = slot & 15;
    const float4* s4 =
        (const float4*)(sentence + (size_t)(g * 32 + f * 16 + l16) * H + kt * 32 + quad * 8);
    // write: consecutive t -> consecutive 16B (1KB/wave). read: 64B per row chunk.
    *(bf16x8*)(packA + (size_t)seg * 512 + slot * 8) = cvt8(s4[0], s4[1]);
  } else if (b < 5632) {
    // ---- phase 2: W_sent [H][A] fp32 -> packB frag-major bf16 ----
    int r = b - 4096;                 // 512 tiles per head
    int head = r >> 9; r &= 511;
    const float* W = head == 0 ? Wp : (head == 1 ? Wc_s : Wh);
    int a0 = (r & 31) * 64;           // 32 a-tiles
    int k0 = (r >> 5) * 64;           // 16 k-tiles
#pragma unroll
    for (int i = 0; i < 8; ++i) {
      int idx = t + i * 256;
      int rr = idx >> 5;              // k-row 0..63
      int cc = (idx & 31) * 2;        // a-col pairs: float2 loads
      float2 w2 = *(const float2*)&W[(size_t)(k0 + rr) * A + a0 + cc];
      tile[cc][rr] = w2.x;            // tile[a_local][k_local]
      tile[cc + 1][rr] = w2.y;
    }
    __syncthreads();
#pragma unroll
    for (int i = 0; i < 2; ++i) {
      int c = t + i * 256;
      int segl = c >> 6;              // 0..7
      int cgl = segl >> 1, ktl = segl & 1;
      int slot = c & 63, quad = slot >> 4, l16 = slot & 15;
      int al = cgl * 16 + l16;
      int kl = ktl * 32 + quad * 8;
      bf16x8 o;
#pragma unroll
      for (int e = 0; e < 8; ++e) o[e] = (__bf16)tile[al][kl + e];
      size_t seg = ((size_t)head * 128 + (a0 >> 4) + cgl) * 32 + (k0 >> 5) + ktl;
      *(bf16x8*)(packB + seg * 512 + slot * 8) = o;
    }
  } else if (b < 5728) {
    // ---- phase 3: ctxb quarter-partials, direct store ----
    int r = b - 5632;                 // 96 blocks: 3 heads x {8 a-blocks x 4 e-quarters}
    int head = r >> 5;
    int sub = r & 31;
    int ablk = sub & 7;
    int eq = sub >> 3;                // e-quarter: 192 elements
    const float* ctx = head == 0 ? ctx_p : (head == 1 ? ctx_c : ctx_h);
    const float* Wc  = head == 0 ? Wcx_p : (head == 1 ? Wcx_c : Wcx_h);
    int a = ablk * 256 + t;
    float s = 0.f;
    if (eq == 0) {
      const float* bs = head == 0 ? bs_p : (head == 1 ? bs_c : bs_h);
      const float* bc = head == 0 ? bc_p : (head == 1 ? bc_c : bc_h);
      s = bs[a] + bc[a];
    }
    int e0 = eq * 192;
#pragma unroll 8
    for (int e = e0; e < e0 + 192; ++e) s = fmaf(ctx[e], Wc[(size_t)e * A + a], s);
    ctxb_q[eq * 3 * A + head * A + a] = s;
  } else {
    // ---- phase 4: zero e_arr (6144 float4) + out ----
    int idx = (b - 5728) * 256 + t;
    float4 z = {0.f, 0.f, 0.f, 0.f};
    int total = 6144 + (n_out >> 2);
    for (int i = idx; i < total; i += 2048) {
      if (i < 6144) ((float4*)e_arr)[i] = z;
      else ((float4*)out)[i - 6144] = z;
    }
  }
}

// ---------- GEMM + fused tanh*v epilogue -> e[head][s] (UNCHANGED from R13) ----------
// 128x128 block, 2x2 waves of 64x64 (4x4 16x16x32 frags). ZERO LDS on the K-path: per
// wave-iter 8 coalesced 1KB register loads feed 16 MFMA (0.5 loads/MFMA). No barriers, no
// manual waitcnt (compiler dataflow vmcnt). x/y double-slot 1-iter-ahead prefetch. XCD panel
// map: xcd=bid&7 owns 6 of 48 (n,head) panels; m outer. LDS only for e_part reduction.
__global__ __launch_bounds__(256)
void k_gemm_e(const __bf16* __restrict__ packA, const __bf16* __restrict__ packB,
              const float* __restrict__ ctxb_q,
              const float* __restrict__ v_p, const float* __restrict__ v_c,
              const float* __restrict__ v_h,
              const int* __restrict__ length, float* __restrict__ e_out) {
  int bid = blockIdx.x;
  int xcd = bid & 7;
  int j = bid >> 3;                  // [0, 384)
  int mt = j / 6;                    // m OUTER within XCD: 64 m-tiles of 128
  int pl = j - mt * 6;               // 6 panels per XCD
  int panel = xcd * 6 + pl;          // [0, 48)
  int n0 = (panel & 15) * 128;
  int head = panel >> 4;

  int m0 = mt * 128;
  int len = min(max(length[0], 0), S);
  if (m0 >= len) return;          // masked rows can never influence the softmax
  const float* v  = head == 0 ? v_p : (head == 1 ? v_c : v_h);
  float* e_h = e_out + head * S;

  __shared__ float e_part[128];

  int tid = threadIdx.x;
  if (tid < 128) e_part[tid] = 0.f;
  __syncthreads();                   // order init before epilogue (no loop barriers exist)

  int lane = tid & 63;
  int wave = tid >> 6;
  int wm = wave >> 1, wn = wave & 1;       // wave tile: 64 rows x 64 cols
  int quad = lane >> 4, l16 = lane & 15;

  f32x4 acc[4][4];
#pragma unroll
  for (int i = 0; i < 4; ++i)
#pragma unroll
    for (int j2 = 0; j2 < 4; ++j2) acc[i][j2] = (f32x4){0.f, 0.f, 0.f, 0.f};

  const __bf16* gA = packA + ((size_t)(m0 >> 5) + wm * 2) * 64 * 512 + (size_t)lane * 8;
  const __bf16* gB =
      packB + (((size_t)head * 128 + (n0 >> 4) + wn * 4) * 32) * 512 + (size_t)lane * 8;

  bf16x8 xa0, xa1, xa2, xa3, ya0, ya1, ya2, ya3;   // A slots (frag 0..3) x2
  bf16x8 xb0, xb1, xb2, xb3, yb0, yb1, yb2, yb3;   // B slots (frag 0..3) x2

#define LOADA(sl, kt)                                                \
  do {                                                               \
    sl##0 = *(const bf16x8*)(gA + ((size_t)((kt)*2 + 0) << 9));      \
    sl##1 = *(const bf16x8*)(gA + ((size_t)((kt)*2 + 1) << 9));      \
    sl##2 = *(const bf16x8*)(gA + ((size_t)(64 + (kt)*2 + 0) << 9)); \
    sl##3 = *(const bf16x8*)(gA + ((size_t)(64 + (kt)*2 + 1) << 9)); \
  } while (0)

#define LOADB(sl, kt)                                            \
  do {                                                           \
    sl##0 = *(const bf16x8*)(gB + ((size_t)(kt) << 9));          \
    sl##1 = *(const bf16x8*)(gB + ((size_t)(32 + (kt)) << 9));   \
    sl##2 = *(const bf16x8*)(gB + ((size_t)(64 + (kt)) << 9));   \
    sl##3 = *(const bf16x8*)(gB + ((size_t)(96 + (kt)) << 9));   \
  } while (0)

#define COMPUTE(asl, bsl)                                                                     \
  do {                                                                                        \
    _Pragma("unroll")                                                                         \
    for (int jj = 0; jj < 4; ++jj) {                                                          \
      bf16x8 bf_ = jj == 0 ? bsl##0 : (jj == 1 ? bsl##1 : (jj == 2 ? bsl##2 : bsl##3));       \
      acc[0][jj] = __builtin_amdgcn_mfma_f32_16x16x32_bf16(asl##0, bf_, acc[0][jj], 0, 0, 0); \
      acc[1][jj] = __builtin_amdgcn_mfma_f32_16x16x32_bf16(asl##1, bf_, acc[1][jj], 0, 0, 0); \
      acc[2][jj] = __builtin_amdgcn_mfma_f32_16x16x32_bf16(asl##2, bf_, acc[2][jj], 0, 0, 0); \
      acc[3][jj] = __builtin_amdgcn_mfma_f32_16x16x32_bf16(asl##3, bf_, acc[3][jj], 0, 0, 0); \
    }                                                                                         \
  } while (0)

  LOADA(xa, 0);
  LOADB(xb, 0);
#pragma unroll 1
  for (int kt = 0; kt < 30; kt += 2) {
    LOADA(ya, kt + 1);
    LOADB(yb, kt + 1);
    COMPUTE(xa, xb);               // compiler waits exactly on xa/xb (counted vmcnt)
    LOADA(xa, kt + 2);
    LOADB(xb, kt + 2);
    COMPUTE(ya, yb);
  }
  LOADA(ya, 31);
  LOADB(yb, 31);
  COMPUTE(xa, xb);                 // kt = 30
  COMPUTE(ya, yb);                 // kt = 31

#undef LOADA
#undef LOADB
#undef COMPUTE

  float vj[4], cbj[4];
#pragma unroll
  for (int j2 = 0; j2 < 4; ++j2) {
    int col = n0 + wn * 64 + j2 * 16 + l16;
    vj[j2] = v[col];
    cbj[j2] = ctxb_q[head * A + col] + ctxb_q[3 * A + head * A + col] +
              ctxb_q[6 * A + head * A + col] + ctxb_q[9 * A + head * A + col];
  }
#pragma unroll
  for (int i = 0; i < 4; ++i) {
#pragma unroll
    for (int r = 0; r < 4; ++r) {
      float p = 0.f;
#pragma unroll
      for (int j2 = 0; j2 < 4; ++j2) {
        float u = acc[i][j2][r] + cbj[j2];
        float ex = __expf(2.f * u);        // tanh = 1 - 2/(e^2x+1); inf-safe at both ends
        float th = 1.f - 2.f / (ex + 1.f);
        p = fmaf(th, vj[j2], p);
      }
      p += __shfl_xor(p, 1);
      p += __shfl_xor(p, 2);
      p += __shfl_xor(p, 4);
      p += __shfl_xor(p, 8);
      if (l16 == 0) atomicAdd(&e_part[wm * 64 + i * 16 + quad * 4 + r], p);
    }
  }
  __syncthreads();
  if (tid < 128) atomicAdd(&e_h[m0 + tid], e_part[tid]);
}

// ---------- out[h] = sum_s w(s) * sentence[s][h]; ONE online stats pass per head ----------
__global__ void k_out(const float* __restrict__ sent, const float* __restrict__ e_arr,
                      const int* __restrict__ length, float* __restrict__ out) {
  int len = min(max(length[0], 0), S);
  int r0 = blockIdx.x * 16;
  if (r0 >= len) return;
  int tid = threadIdx.x;

  __shared__ float redm[3][4], reds[3][4];
  __shared__ float sstat[6];    // m0,s0,m1,s1,m2,s2
  __shared__ float wrow[16];

  // single online (max,sum) pass per head
#pragma unroll
  for (int h = 0; h < 3; ++h) {
    const float* e_h = e_arr + h * S;
    float m = -3.4e38f, ss = 0.f;
    for (int s = tid; s < len; s += 256) {
      float e = e_h[s];
      if (e > m) { ss = ss * __expf(m - e) + 1.f; m = e; }
      else ss += __expf(e - m);
    }
#pragma unroll
    for (int o = 32; o >= 1; o >>= 1) {
      float mo = __shfl_xor(m, o), so = __shfl_xor(ss, o);
      float mn = fmaxf(m, mo);
      ss = ss * __expf(m - mn) + so * __expf(mo - mn);
      m = mn;
    }
    if ((tid & 63) == 0) { redm[h][tid >> 6] = m; reds[h][tid >> 6] = ss; }
  }
  __syncthreads();
  if (tid < 3) {
    float m = redm[tid][0], s = reds[tid][0];
#pragma unroll
    for (int w = 1; w < 4; ++w) {
      float mo = redm[tid][w], so = reds[tid][w];
      float mn = fmaxf(m, mo);
      s = s * __expf(m - mn) + so * __expf(mo - mn);
      m = mn;
    }
    sstat[tid * 2] = m;
    sstat[tid * 2 + 1] = s;
  }
  __syncthreads();

  if (tid < 16 && r0 + tid < len) {
    int r = r0 + tid;
    wrow[tid] = (__expf(e_arr[r] - sstat[0]) / sstat[1] +
                 __expf(e_arr[S + r] - sstat[2]) / sstat[3] +
                 __expf(e_arr[2 * S + r] - sstat[4]) / sstat[5]) * (1.f / 3.f);
  }
  __syncthreads();

  int col = tid * 4;
  int rend = min(r0 + 16, len);
  float4 acc = {0.f, 0.f, 0.f, 0.f};
  for (int r = r0; r < rend; ++r) {
    float w = wrow[r - r0];
    float4 x = *(const float4*)(sent + (size_t)r * H + col);
    acc.x = fmaf(w, x.x, acc.x);
    acc.y = fmaf(w, x.y, acc.y);
    acc.z = fmaf(w, x.z, acc.z);
    acc.w = fmaf(w, x.w, acc.w);
  }
  atomicAdd(&out[col + 0], acc.x);
  atomicAdd(&out[col + 1], acc.y);
  atomicAdd(&out[col + 2], acc.z);
  atomicAdd(&out[col + 3], acc.w);
}

}  // namespace

extern "C" void kernel_launch(void* const* d_in, const int* in_sizes, int n_in,
                              void* d_out, int out_size, void* d_ws, size_t ws_size,
                              hipStream_t stream) {
  const float* sentence = (const float*)d_in[0];
  const int* length     = (const int*)d_in[1];
  const float* ctx_p = (const float*)d_in[2];
  const float* ctx_c = (const float*)d_in[3];
  const float* ctx_h = (const float*)d_in[4];
  const float* W_s[3] = {(const float*)d_in[5],  (const float*)d_in[11], (const float*)d_in[17]};
  const float* b_s[3] = {(const float*)d_in[6],  (const float*)d_in[12], (const float*)d_in[18]};
  const float* W_c[3] = {(const float*)d_in[7],  (const float*)d_in[13], (const float*)d_in[19]};
  const float* b_c[3] = {(const float*)d_in[8],  (const float*)d_in[14], (const float*)d_in[20]};
  const float* v_[3]  = {(const float*)d_in[9],  (const float*)d_in[15], (const float*)d_in[21]};
  float* out = (float*)d_out;

  // workspace layout (bytes)
  char* ws = (char*)d_ws;
  __bf16* packA  = (__bf16*)(ws);               // 8192*1024*2   = 16777216 (fragment-major)
  __bf16* packB  = (__bf16*)(ws + 16777216);    // 3*2048*1024*2 = 12582912 (fragment-major)
  float* ctxb_q  = (float*)(ws + 29360128);     // 4*3*2048*4    = 98304
  float* e_arr   = (float*)(ws + 29458432);     // 3*8192*4      = 98304

  // 3 graph nodes, no memsets, no cross-kernel atomics except e_arr/out (zeroed in prep).
  k_prep<<<5736, 256, 0, stream>>>(sentence, packA,
                                   W_s[0], W_s[1], W_s[2], packB,
                                   ctx_p, ctx_c, ctx_h,
                                   W_c[0], W_c[1], W_c[2],
                                   b_s[0], b_s[1], b_s[2],
                                   b_c[0], b_c[1], b_c[2], ctxb_q, e_arr,
                                   length, out, out_size);
  k_gemm_e<<<3072, 256, 0, stream>>>(packA, packB, ctxb_q,
                                     v_[0], v_[1], v_[2], length, e_arr);
  k_out<<<S / 16, 256, 0, stream>>>(sentence, e_arr, length, out);
}